// Round 10
// baseline (248.995 us; speedup 1.0000x reference)
//
#include <hip/hip_runtime.h>
#include <hip/hip_bf16.h>

#define IN_F 8192
#define OUT_F 8192
#define SEQ 64
#define LORA_R 16

typedef __attribute__((ext_vector_type(4))) float f32x4;
typedef __attribute__((ext_vector_type(4))) int i32x4;
typedef __attribute__((ext_vector_type(4))) unsigned short u16x4;
typedef _Float16 f16x2 __attribute__((ext_vector_type(2)));
typedef _Float16 f16x8 __attribute__((ext_vector_type(8)));

typedef __attribute__((address_space(3))) unsigned int lds_u32;
typedef const __attribute__((address_space(1))) unsigned int glb_u32;

__device__ __forceinline__ void gl_lds16(const void* g, void* l) {
    __builtin_amdgcn_global_load_lds((glb_u32*)g, (lds_u32*)l, 16, 0, 0);
}

#define VMCNT(n) asm volatile("s_waitcnt vmcnt(" #n ")" ::: "memory")

// ---- prep (measured, R5/R8 verbatim): xb = fp16(x); t partials = x@A^T (K/4). ----
__global__ __launch_bounds__(256) void k_prep(
    const float* __restrict__ x, const float* __restrict__ A,
    unsigned short* __restrict__ xb, float* __restrict__ t) {
    __shared__ float part[64];
    const int s = blockIdx.x >> 2, p = blockIdx.x & 3;
    const int w = threadIdx.x >> 6, lane = threadIdx.x & 63;
    const int kbase = p * 2048 + w * 512;
    const float* xr = x + s * IN_F + kbase;

    f32x4 xv[2];
    #pragma unroll
    for (int j = 0; j < 2; ++j) {
        xv[j] = *(const f32x4*)(xr + j * 256 + lane * 4);
        u16x4 h;
        h[0] = __builtin_bit_cast(unsigned short, (_Float16)xv[j].x);
        h[1] = __builtin_bit_cast(unsigned short, (_Float16)xv[j].y);
        h[2] = __builtin_bit_cast(unsigned short, (_Float16)xv[j].z);
        h[3] = __builtin_bit_cast(unsigned short, (_Float16)xv[j].w);
        *(u16x4*)(xb + s * IN_F + kbase + j * 256 + lane * 4) = h;
    }

    float acc[LORA_R];
    #pragma unroll
    for (int r = 0; r < LORA_R; ++r) acc[r] = 0.f;
    #pragma unroll
    for (int r = 0; r < LORA_R; ++r) {
        const float* ar = A + r * IN_F + kbase;
        #pragma unroll
        for (int j = 0; j < 2; ++j) {
            f32x4 av = *(const f32x4*)(ar + j * 256 + lane * 4);
            acc[r] = fmaf(xv[j].x, av.x, acc[r]);
            acc[r] = fmaf(xv[j].y, av.y, acc[r]);
            acc[r] = fmaf(xv[j].z, av.z, acc[r]);
            acc[r] = fmaf(xv[j].w, av.w, acc[r]);
        }
    }
    #pragma unroll
    for (int r = 0; r < LORA_R; ++r) {
        float v = acc[r];
        #pragma unroll
        for (int off = 32; off; off >>= 1) v += __shfl_down(v, off, 64);
        if (lane == 0) part[w * 16 + r] = v;
    }
    __syncthreads();
    if (threadIdx.x < 16)
        t[s * 64 + p * 16 + threadIdx.x] = part[threadIdx.x] + part[16 + threadIdx.x] +
                                           part[32 + threadIdx.x] + part[48 + threadIdx.x];
}

// ---- main: 256 blocks (32-col tile, FULL K), 512 thr = 8 waves, BK=256 ----
// W ONLY in LDS: gl_lds, 4 buffers x 16KB, issue-ahead 3, XOR-swizzled (as R8).
// x A-fragments read DIRECTLY from xb global (L2/L3-resident) into regs each iter
// -> no x LDS traffic, no x staging barrier coupling, no explicit in-loop vmcnt:
// compiler's wait on iter kt-1's x-frag regs (issued after W(kt+2)'s gl_lds)
// retires all older gl_lds by FIFO -> W(kt) provably resident at barrier(kt).
// LDS (73984 B): wt 4x16384 @0 | scs [32][132] f16 @65536
// epilogue alias: accs[8][64*17] f32 @0; tred[64][16] f32 @36864.
__global__ __launch_bounds__(512, 2) void k_main(
    const int* __restrict__ packed, const float* __restrict__ scales,
    const unsigned short* __restrict__ xb, const float* __restrict__ t,
    const float* __restrict__ B, float* __restrict__ out) {
    __shared__ char lds[73984];
    int* wt = (int*)lds;                         // 4 x 4096 int
    _Float16* scs = (_Float16*)(lds + 65536);    // 32 x 132 f16
    float* accs = (float*)lds;
    float* tred = (float*)(lds + 36864);

    const int tid = threadIdx.x;
    const int n0 = blockIdx.x * 32;
    const int w = tid >> 6, lane = tid & 63;
    const int nh = w >> 2, wkk = w & 3;
    const int q = lane >> 4, c16 = lane & 15;
    const int l5 = lane >> 5, l31 = lane & 31;

    // ---- scales staging: f32 -> f16 once (vm load drained by cvt use) ----
    {
        int row = tid >> 4, g = tid & 15;
        const float* sp = scales + (n0 + row) * (IN_F / 64);
        f32x4 a = *(const f32x4*)(sp + g * 4);
        f32x4 b = *(const f32x4*)(sp + 64 + g * 4);
        u16x4 ha, hb;
        ha[0] = __builtin_bit_cast(unsigned short, (_Float16)a.x);
        ha[1] = __builtin_bit_cast(unsigned short, (_Float16)a.y);
        ha[2] = __builtin_bit_cast(unsigned short, (_Float16)a.z);
        ha[3] = __builtin_bit_cast(unsigned short, (_Float16)a.w);
        hb[0] = __builtin_bit_cast(unsigned short, (_Float16)b.x);
        hb[1] = __builtin_bit_cast(unsigned short, (_Float16)b.y);
        hb[2] = __builtin_bit_cast(unsigned short, (_Float16)b.z);
        hb[3] = __builtin_bit_cast(unsigned short, (_Float16)b.w);
        *(u16x4*)((unsigned short*)scs + row * 132 + g * 4) = ha;
        *(u16x4*)((unsigned short*)scs + row * 132 + 64 + g * 4) = hb;
    }
    __builtin_amdgcn_sched_barrier(0);   // pin scs code before gl_lds prologue

    // ---- W staging sources (16B slot pre-XOR'd with row&7), as R8 ----
    const int wr0 = 4 * w + l5, wr1 = wr0 + 2;
    const int* wg0 = packed + (size_t)(n0 + wr0) * (IN_F / 2) + ((l31 ^ (wr0 & 7)) << 2);
    const int* wg1 = packed + (size_t)(n0 + wr1) * (IN_F / 2) + ((l31 ^ (wr1 & 7)) << 2);
    int* wd = wt + w * 512;                      // + buf*4096 (+256 for 2nd)

    // ---- x fragment pointers (direct global reads; rows mt*16+c16) ----
    const _Float16* xf[4];
    #pragma unroll
    for (int mt = 0; mt < 4; ++mt)
        xf[mt] = (const _Float16*)xb + (size_t)(mt * 16 + c16) * IN_F + (4 * wkk + q) * 8;

    // ---- loop-invariant swizzled W read offsets (R8 verbatim) ----
    const int row_w = nh * 16 + c16, r7 = c16 & 7;
    const int pvo0 = row_w * 128 + ((4 * wkk + q) ^ r7) * 4;
    const int pvo1 = row_w * 128 + ((4 * (wkk + 4) + q) ^ r7) * 4;
    const int scso = row_w * 132 + (wkk >> 1);

    f32x4 acc[4];
    #pragma unroll
    for (int mt = 0; mt < 4; ++mt) acc[mt] = (f32x4){0.f, 0.f, 0.f, 0.f};

    // ---- prologue: stage W chunks 0,1,2 -> buffers 0,1,2 ----
    #pragma unroll
    for (int c = 0; c < 3; ++c) {
        gl_lds16(wg0 + (size_t)c * 128, wd + c * 4096);
        gl_lds16(wg1 + (size_t)c * 128, wd + c * 4096 + 256);
    }
    VMCNT(4);                                            // W chunk 0 resident
    asm volatile("s_waitcnt lgkmcnt(0)" ::: "memory");   // scs visible
    __builtin_amdgcn_s_barrier();

    const f16x2 c1032 = {(_Float16)1032.0f, (_Float16)1032.0f};

    for (int kt = 0; kt < 32; ++kt) {
        __builtin_amdgcn_s_barrier();
        __builtin_amdgcn_sched_barrier(0);
        const int cb = kt & 3;
        // x fragments for THIS iter: per-lane 16B global loads (L2-hot)
        f16x8 af0[4], af1[4];
        #pragma unroll
        for (int mt = 0; mt < 4; ++mt) {
            af0[mt] = *(const f16x8*)(xf[mt] + kt * 256);
            af1[mt] = *(const f16x8*)(xf[mt] + kt * 256 + 128);
        }
        // W prefetch chunk kt+3 (visibility via FIFO + next barriers)
        if (kt <= 28) {
            const size_t wo = (size_t)(kt + 3) * 128;
            const int nb = (kt + 3) & 3;
            gl_lds16(wg0 + wo, wd + nb * 4096);
            gl_lds16(wg1 + wo, wd + nb * 4096 + 256);
        }
        // dequant W chunk kt from LDS
        i32x4 pv0 = *(const i32x4*)(wt + cb * 4096 + pvo0);
        i32x4 pv1 = *(const i32x4*)(wt + cb * 4096 + pvo1);
        _Float16 s0 = scs[scso + kt * 4];
        _Float16 s1 = scs[scso + kt * 4 + 2];
        f16x2 sc0 = {s0, s0}, sc1 = {s1, s1};
        f16x8 bf0, bf1;
        #pragma unroll
        for (int m = 0; m < 4; ++m) {
            unsigned u0 = ((((unsigned)pv0[m] << 12) | (unsigned)pv0[m]) & 0x000F000Fu) | 0x64006400u;
            unsigned u1 = ((((unsigned)pv1[m] << 12) | (unsigned)pv1[m]) & 0x000F000Fu) | 0x64006400u;
            f16x2 h0 = __builtin_bit_cast(f16x2, u0);
            f16x2 h1 = __builtin_bit_cast(f16x2, u1);
            h0 = (h0 - c1032) * sc0;         // exact (q-8)*scale
            h1 = (h1 - c1032) * sc1;
            bf0[2 * m] = h0.x; bf0[2 * m + 1] = h0.y;
            bf1[2 * m] = h1.x; bf1[2 * m + 1] = h1.y;
        }
        #pragma unroll
        for (int mt = 0; mt < 4; ++mt)
            acc[mt] = __builtin_amdgcn_mfma_f32_16x16x32_f16(af0[mt], bf0, acc[mt], 0, 0, 0);
        #pragma unroll
        for (int mt = 0; mt < 4; ++mt)
            acc[mt] = __builtin_amdgcn_mfma_f32_16x16x32_f16(af1[mt], bf1, acc[mt], 0, 0, 0);
    }
    __syncthreads();   // all waves done with wt/scs before alias overwrite

    // ---- epilogue (R8 verbatim): partials -> LDS, t reduce, LoRA, store ----
    float* myacc = accs + w * (64 * 17);
    #pragma unroll
    for (int mt = 0; mt < 4; ++mt)
        #pragma unroll
        for (int r = 0; r < 4; ++r)
            myacc[(mt * 16 + q * 4 + r) * 17 + c16] = acc[mt][r];
    #pragma unroll
    for (int jj = 0; jj < 2; ++jj) {
        int p2 = tid + jj * 512;                  // 1024 = 64 s x 16 r
        const float* tp = t + (p2 >> 4) * 64 + (p2 & 15);
        tred[p2] = tp[0] + tp[16] + tp[32] + tp[48];
    }
    __syncthreads();

    #pragma unroll
    for (int j = 0; j < 4; ++j) {
        int p = tid + j * 512;                    // 2048 outputs: s in 0..63, c in 0..31
        int s = p >> 5, c = p & 31;
        const float* ab = accs + (c >> 4) * 4 * (64 * 17) + s * 17 + (c & 15);
        float v = ab[0] + ab[64 * 17] + ab[2 * 64 * 17] + ab[3 * 64 * 17];
        const float* trow = tred + s * 16;
        const float* bp = B + (n0 + c) * LORA_R;
        f32x4 t0 = *(const f32x4*)trow,        t1 = *(const f32x4*)(trow + 4);
        f32x4 t2 = *(const f32x4*)(trow + 8),  t3 = *(const f32x4*)(trow + 12);
        f32x4 b0 = *(const f32x4*)bp,       b1 = *(const f32x4*)(bp + 4);
        f32x4 b2 = *(const f32x4*)(bp + 8), b3 = *(const f32x4*)(bp + 12);
        float lr = t0.x * b0.x + t0.y * b0.y + t0.z * b0.z + t0.w * b0.w
                 + t1.x * b1.x + t1.y * b1.y + t1.z * b1.z + t1.w * b1.w
                 + t2.x * b2.x + t2.y * b2.y + t2.z * b2.z + t2.w * b2.w
                 + t3.x * b3.x + t3.y * b3.y + t3.z * b3.z + t3.w * b3.w;
        v += 2.0f * lr;
        out[s * OUT_F + n0 + c] = v;
    }
}

extern "C" void kernel_launch(void* const* d_in, const int* in_sizes, int n_in,
                              void* d_out, int out_size, void* d_ws, size_t ws_size,
                              hipStream_t stream) {
    const float* x      = (const float*)d_in[0];
    const int* packed   = (const int*)d_in[1];
    const float* scales = (const float*)d_in[2];
    const float* lora_A = (const float*)d_in[3];
    const float* lora_B = (const float*)d_in[4];
    float* out = (float*)d_out;

    unsigned short* xb = (unsigned short*)d_ws;                    // 1 MiB fp16 x
    float* t = (float*)((char*)d_ws + (size_t)SEQ * IN_F * 2);     // 16 KiB partials

    k_prep<<<256, 256, 0, stream>>>(x, lora_A, xb, t);
    k_main<<<256, 512, 0, stream>>>(packed, scales, xb, t, lora_B, out);
}